// Round 3
// baseline (898.417 us; speedup 1.0000x reference)
//
#include <hip/hip_runtime.h>
#include <utility>

// 16-wire statevector sim, batch 128. Register-blocked gate sweeps:
// each thread holds 16 amps (4 index bits) in registers; gates on those bits
// are applied in-register. CNOTs with out-of-group control = conditional
// swap (or pure address-XOR fold at write). Wire w <-> global bit (15-w).
//
// Per layer l (r=l+1):
//  pass1: pure-register (no LDS): group global bits {15,14,15-r,14-r}:
//         H2(l-1) folded into load-addr XOR; Rot{0,1,r,r+1}; CNOT(0->r),(1->r+1)
//  pass2: chunk = fixed global bits {15,14}; LDS-staged register sweeps
//         S1{13..10} S2{9..6} S3{5..2} S4{3..0} (+S5{13..10} wraps, r>=3):
//         Rots + ring CNOTs not touching wires 0,1
//  pass3: pure-register readout: H2(5) folded into load-addr XOR; <Z_i>

#define NW    16
#define BLK   1024
#define CHUNK 16384

// ---------- static_for ----------
template<class F, int... Is>
__device__ __forceinline__ void static_for_impl(F&& f, std::integer_sequence<int, Is...>) {
    (f(std::integral_constant<int, Is>{}), ...);
}
template<int N, class F>
__device__ __forceinline__ void static_for(F&& f) {
    static_for_impl(f, std::make_integer_sequence<int, N>{});
}

// ---------- gate primitives (all register-index-static) ----------
__device__ __forceinline__ void c2x2(float2& a0, float2& a1,
                                     float2 m00, float2 m01,
                                     float2 m10, float2 m11) {
    float2 r0, r1;
    r0.x = m00.x*a0.x - m00.y*a0.y + m01.x*a1.x - m01.y*a1.y;
    r0.y = m00.x*a0.y + m00.y*a0.x + m01.x*a1.y + m01.y*a1.x;
    r1.x = m10.x*a0.x - m10.y*a0.y + m11.x*a1.x - m11.y*a1.y;
    r1.y = m10.x*a0.y + m10.y*a0.x + m11.x*a1.y + m11.y*a1.x;
    a0 = r0; a1 = r1;
}

template<int Q>
__device__ __forceinline__ void rot_regs(float2 a[16], float2 m00, float2 m01,
                                         float2 m10, float2 m11) {
#pragma unroll
    for (int j = 0; j < 16; ++j)
        if (!((j >> Q) & 1))
            c2x2(a[j], a[j | (1 << Q)], m00, m01, m10, m11);
}

template<int QC, int QT>
__device__ __forceinline__ void cnot_inreg(float2 a[16]) {   // free: reg rename
#pragma unroll
    for (int j = 0; j < 16; ++j)
        if (((j >> QC) & 1) && !((j >> QT) & 1)) {
            float2 t = a[j]; a[j] = a[j | (1 << QT)]; a[j | (1 << QT)] = t;
        }
}

template<int QT>
__device__ __forceinline__ void cnot_ctrlout(float2 a[16], int ctrl) {
#pragma unroll
    for (int j = 0; j < 16; ++j)
        if (!((j >> QT) & 1)) {
            int j2 = j | (1 << QT);
            float2 x = a[j], y = a[j2];
            a[j].x  = ctrl ? y.x : x.x;  a[j].y  = ctrl ? y.y : x.y;
            a[j2].x = ctrl ? x.x : y.x;  a[j2].y = ctrl ? x.y : y.y;
        }
}

// Rot(phi,theta,omega) = RZ(omega) RY(theta) RZ(phi)
__device__ __forceinline__ void rot_mat(const float* ww, float2 m[4]) {
    float phi = ww[0], th = ww[1], om = ww[2];
    float ct, st;   sincosf(0.5f * th, &st, &ct);
    float cap, sap; sincosf(0.5f * (phi + om), &sap, &cap);
    float cam, sam; sincosf(0.5f * (phi - om), &sam, &cam);
    m[0] = make_float2( cap * ct, -sap * ct);
    m[1] = make_float2(-cam * st, -sam * st);
    m[2] = make_float2( cam * st, -sam * st);
    m[3] = make_float2( cap * ct,  sap * ct);
}

__device__ __forceinline__ void prep_gm(float2 (*gm)[4], const float* w, int l) {
    int t = threadIdx.x;
    if (t < NW) rot_mat(w + (l * NW + t) * 3, gm[t]);
}

// ---------- pass2 sweep gate driver ----------
// returns wmask: XOR mask (in group-nibble space) to fold into write addresses
template<int L, int S>
__device__ __forceinline__ int sweep_gates(float2 a[16], const float2 (*gm)[4], int ub) {
    constexpr int r = L + 1;
    constexpr int base = (S == 2) ? 6 : (S == 3) ? 2 : (S == 4) ? 0 : 10;
    int wmask = 0;
    if constexpr (S <= 4) {
        constexpr int plo = (S == 1) ? 10 : (S == 2) ? 6 : (S == 3) ? 2 : 0;
        constexpr int phi = (S == 1) ? 13 : (S == 2) ? 9 : (S == 3) ? 5 : 1;
        // Rots, descending bit (wires of this partition; fixed-wire rots were done in pass1)
        static_for<phi - plo + 1>([&](auto K) {
            constexpr int bb = phi - decltype(K)::value;
            if constexpr (bb != 15 - r && bb != 14 - r) {
                constexpr int wire = 15 - bb;
                rot_regs<bb - base>(a, gm[wire][0], gm[wire][1], gm[wire][2], gm[wire][3]);
            }
        });
        // ring CNOTs, ascending i: i=2..15-r, cb=15-i, tb=cb-r
        static_for<14 - r>([&](auto K) {
            constexpr int i  = 2 + decltype(K)::value;
            constexpr int cb = 15 - i, tb = cb - r;
            if constexpr (tb >= plo && tb <= phi) {
                if constexpr (cb <= base + 3) {
                    cnot_inreg<cb - base, tb - base>(a);        // control in group: free
                } else if constexpr (tb - r >= plo) {
                    cnot_ctrlout<tb - base>(a, (ub >> cb) & 1); // same-sweep successor: now
                } else {
                    wmask |= ((ub >> cb) & 1) << (tb - base);   // fold into write addr
                }
            }
        });
    } else {
        // S5: wrap CNOTs i=18-r..15 (cb=15-i, tb=31-i-r), all disjoint: fold all
        static_for<(r >= 3) ? (r - 2) : 0>([&](auto K) {
            constexpr int i  = 18 - r + decltype(K)::value;
            constexpr int cb = 15 - i, tb = 31 - i - r;
            wmask |= ((ub >> cb) & 1) << (tb - 10);
        });
    }
    return wmask;
}

// ---------- pass1: pure register, group global bits {15,14,g1,g0} ----------
template<int L>
__global__ __launch_bounds__(BLK, 4)
void k_pass1(const float* __restrict__ x, const float* __restrict__ w,
             float2* __restrict__ psi) {
    constexpr int r  = L + 1;
    constexpr int g1 = (L == 0) ? 13 : 15 - r;
    constexpr int g0 = (L == 0) ? 12 : 14 - r;
    const int b = blockIdx.x >> 2;
    const int T = ((blockIdx.x & 3) << 10) | threadIdx.x;   // 12-bit
    float2* g = psi + ((size_t)b << 16);

    // deposit T into the 12 non-group positions (0..13 minus {g1,g0})
    int sb;
    {
        constexpr int lobits  = g0;
        constexpr int midbits = g1 - 1 - g0;
        int lo  = T & ((1 << lobits) - 1);
        int mid = (T >> lobits) & ((1 << midbits) - 1);
        int hi  = T >> (lobits + midbits);
        sb = lo | (mid << (g0 + 1)) | (hi << (g1 + 1));
    }

    float2 m0[4], m1[4], mr[4], mr1[4];
    rot_mat(w + (L * NW + 0) * 3, m0);
    rot_mat(w + (L * NW + 1) * 3, m1);
    if constexpr (L == 0) {
        rot_mat(w + 2 * 3, mr);
    } else {
        rot_mat(w + (L * NW + r) * 3, mr);
        rot_mat(w + (L * NW + r + 1) * 3, mr1);
    }

    // H2(L-1) (targets wires 0,1 = bits 15,14) folded into load-address XOR
    int smask = 0;
    if constexpr (L >= 2)
        smask = (((sb >> (L - 1)) & 1) << 15) | (((sb >> (L - 2)) & 1) << 14);
    else if constexpr (L == 1)
        smask = ((sb >> 0) & 1) << 15;

    float2 a[16];
    if constexpr (L == 0) {
        // AngleEmbedding product state, built in registers
        float cv[NW], sv[NW];
#pragma unroll
        for (int wq = 0; wq < NW; ++wq)
            sincosf(0.5f * x[b * NW + wq], &sv[wq], &cv[wq]);
        float common = 1.0f;
#pragma unroll
        for (int wq = 4; wq < NW; ++wq) {
            int bit = (sb >> (15 - wq)) & 1;
            common *= bit ? sv[wq] : cv[wq];
        }
#pragma unroll
        for (int j = 0; j < 16; ++j) {
            float f0 = (j & 8) ? sv[0] : cv[0];
            float f1 = (j & 4) ? sv[1] : cv[1];
            float f2 = (j & 2) ? sv[2] : cv[2];
            float f3 = (j & 1) ? sv[3] : cv[3];
            a[j] = make_float2(common * f0 * f1 * f2 * f3, 0.0f);
        }
    } else {
#pragma unroll
        for (int j = 0; j < 16; ++j) {
            int s = (sb | ((j & 1) << g0) | (((j >> 1) & 1) << g1)
                        | (((j >> 2) & 1) << 14) | (((j >> 3) & 1) << 15)) ^ smask;
            a[j] = g[s];
        }
    }

    rot_regs<3>(a, m0[0], m0[1], m0[2], m0[3]);   // Rot wire 0
    rot_regs<2>(a, m1[0], m1[1], m1[2], m1[3]);   // Rot wire 1
    if constexpr (L == 0) {
        rot_regs<1>(a, mr[0], mr[1], mr[2], mr[3]);  // Rot wire 2
        cnot_inreg<3, 2>(a);                          // CNOT(0->1)
        cnot_inreg<2, 1>(a);                          // CNOT(1->2)
    } else {
        rot_regs<1>(a, mr[0],  mr[1],  mr[2],  mr[3]);   // Rot wire r
        rot_regs<0>(a, mr1[0], mr1[1], mr1[2], mr1[3]);  // Rot wire r+1
        cnot_inreg<3, 1>(a);                              // CNOT(0->r)
        cnot_inreg<2, 0>(a);                              // CNOT(1->r+1)
    }

#pragma unroll
    for (int j = 0; j < 16; ++j) {
        int s = sb | ((j & 1) << g0) | (((j >> 1) & 1) << g1)
                   | (((j >> 2) & 1) << 14) | (((j >> 3) & 1) << 15);
        g[s] = a[j];
    }
}

// ---------- pass2: LDS-staged register sweeps, fixed global bits {15,14} ----------
template<int L>
__global__ __launch_bounds__(BLK, 4)
void k_pass2(const float* __restrict__ w, float2* __restrict__ psi) {
    constexpr int r = L + 1;
    __shared__ float2 lds[CHUNK + CHUNK / 16];   // padded: idx = u + (u>>4)
    __shared__ float2 gm[NW][4];
    const int b = blockIdx.x >> 2, c = blockIdx.x & 3;
    const int tid = threadIdx.x;
    float2* g = psi + ((size_t)b << 16) + ((size_t)c << 14);

    prep_gm(gm, w, L);
    __syncthreads();

    float2 a[16];

    { // S1: group {13..10}: global -> regs -> LDS
        const int ub = tid;
#pragma unroll
        for (int j = 0; j < 16; ++j) a[j] = g[ub | (j << 10)];
        int wm = sweep_gates<L, 1>(a, gm, ub) << 10;
#pragma unroll
        for (int j = 0; j < 16; ++j) {
            int u = (ub | (j << 10)) ^ wm;
            lds[u + (u >> 4)] = a[j];
        }
    }
    __syncthreads();
    { // S2: group {9..6}
        const int ub = (tid & 63) | ((tid >> 6) << 10);
#pragma unroll
        for (int j = 0; j < 16; ++j) { int u = ub | (j << 6); a[j] = lds[u + (u >> 4)]; }
        int wm = sweep_gates<L, 2>(a, gm, ub) << 6;
#pragma unroll
        for (int j = 0; j < 16; ++j) {
            int u = (ub | (j << 6)) ^ wm;
            lds[u + (u >> 4)] = a[j];
        }
    }
    __syncthreads();
    { // S3: group {5..2}
        const int ub = (tid & 3) | ((tid >> 2) << 6);
#pragma unroll
        for (int j = 0; j < 16; ++j) { int u = ub | (j << 2); a[j] = lds[u + (u >> 4)]; }
        int wm = sweep_gates<L, 3>(a, gm, ub) << 2;
#pragma unroll
        for (int j = 0; j < 16; ++j) {
            int u = (ub | (j << 2)) ^ wm;
            lds[u + (u >> 4)] = a[j];
        }
    }
    __syncthreads();
    { // S4: group {3..0}
        const int ub = tid << 4;
#pragma unroll
        for (int j = 0; j < 16; ++j) { int u = ub | j; a[j] = lds[u + (u >> 4)]; }
        int wm = sweep_gates<L, 4>(a, gm, ub);
#pragma unroll
        for (int j = 0; j < 16; ++j) {
            int u = (ub | j) ^ wm;
            lds[u + (u >> 4)] = a[j];
        }
    }
    __syncthreads();
    if constexpr (r >= 3) {
        // S5: group {13..10}: wrap CNOTs folded into global store addresses
        const int ub = tid;
#pragma unroll
        for (int j = 0; j < 16; ++j) { int u = ub | (j << 10); a[j] = lds[u + (u >> 4)]; }
        int wm = sweep_gates<L, 5>(a, gm, ub) << 10;
#pragma unroll
        for (int j = 0; j < 16; ++j) g[(ub | (j << 10)) ^ wm] = a[j];
    } else {
        // plain copy LDS -> global (coalesced float4)
#pragma unroll
        for (int it = 0; it < 8; ++it) {
            int v = tid + it * BLK;
            int u = 2 * v;
            float2 lo = lds[u + (u >> 4)];
            float2 hi = lds[u + 1 + (u >> 4)];
            reinterpret_cast<float4*>(g)[v] = make_float4(lo.x, lo.y, hi.x, hi.y);
        }
    }
}

// ---------- pass3: pure register readout, group {15,14,1,0} ----------
__global__ __launch_bounds__(BLK, 4)
void k_pass3(const float2* __restrict__ psi, float* __restrict__ out) {
    const int b = blockIdx.x >> 2;
    const int T = ((blockIdx.x & 3) << 10) | threadIdx.x;   // 12-bit
    const float2* g = psi + ((size_t)b << 16);
    const int sb = T << 2;                                   // non-group = bits 2..13

    // H2(5): CNOT(wire10->0), CNOT(wire11->1): ctrl bits 5,4 -> fold into load addr
    const int smask = (((sb >> 5) & 1) << 15) | (((sb >> 4) & 1) << 14);

    float2 a[16];
#pragma unroll
    for (int jh = 0; jh < 4; ++jh) {
        const float4* p = reinterpret_cast<const float4*>(g + ((sb | (jh << 14)) ^ smask));
        float4 v0 = p[0], v1 = p[1];
        a[jh * 4 + 0] = make_float2(v0.x, v0.y);
        a[jh * 4 + 1] = make_float2(v0.z, v0.w);
        a[jh * 4 + 2] = make_float2(v1.x, v1.y);
        a[jh * 4 + 3] = make_float2(v1.z, v1.w);
    }

    // z for wires 0,1 from j bits 3,2; wires 14,15 from j bits 1,0; rest from sb
    float psum = 0.f, z0 = 0.f, z1 = 0.f, z14 = 0.f, z15 = 0.f;
#pragma unroll
    for (int j = 0; j < 16; ++j) {
        float2 v = a[j];
        float p = v.x * v.x + v.y * v.y;
        psum += p;
        z0  += (j & 8) ? -p : p;
        z1  += (j & 4) ? -p : p;
        z14 += (j & 2) ? -p : p;
        z15 += (j & 1) ? -p : p;
    }
    float z[NW];
    z[0] = z0; z[1] = z1; z[14] = z14; z[15] = z15;
#pragma unroll
    for (int i = 2; i < 14; ++i)
        z[i] = ((sb >> (15 - i)) & 1) ? -psum : psum;

    __shared__ float acc[NW];
    if (threadIdx.x < NW) acc[threadIdx.x] = 0.f;
    __syncthreads();
#pragma unroll
    for (int i = 0; i < NW; ++i) {
        float v = z[i];
#pragma unroll
        for (int off = 32; off > 0; off >>= 1) v += __shfl_down(v, off, 64);
        if ((threadIdx.x & 63) == 0) atomicAdd(&acc[i], v);
    }
    __syncthreads();
    if (threadIdx.x < NW) atomicAdd(&out[b * NW + threadIdx.x], acc[threadIdx.x]);
}

extern "C" void kernel_launch(void* const* d_in, const int* in_sizes, int n_in,
                              void* d_out, int out_size, void* d_ws, size_t ws_size,
                              hipStream_t stream) {
    const float* x = (const float*)d_in[0];   // (B, 16) float32
    const float* w = (const float*)d_in[1];   // (6, 16, 3) float32
    float* out = (float*)d_out;               // (B, 16) float32
    float2* psi = (float2*)d_ws;              // B * 65536 * 8 B = 64 MiB

    const int batch = in_sizes[0] / NW;
    const int grid  = batch * 4;

    hipMemsetAsync(d_out, 0, (size_t)out_size * sizeof(float), stream);

    k_pass1<0><<<grid, BLK, 0, stream>>>(x, w, psi);
    k_pass2<0><<<grid, BLK, 0, stream>>>(w, psi);
    k_pass1<1><<<grid, BLK, 0, stream>>>(x, w, psi);
    k_pass2<1><<<grid, BLK, 0, stream>>>(w, psi);
    k_pass1<2><<<grid, BLK, 0, stream>>>(x, w, psi);
    k_pass2<2><<<grid, BLK, 0, stream>>>(w, psi);
    k_pass1<3><<<grid, BLK, 0, stream>>>(x, w, psi);
    k_pass2<3><<<grid, BLK, 0, stream>>>(w, psi);
    k_pass1<4><<<grid, BLK, 0, stream>>>(x, w, psi);
    k_pass2<4><<<grid, BLK, 0, stream>>>(w, psi);
    k_pass1<5><<<grid, BLK, 0, stream>>>(x, w, psi);
    k_pass2<5><<<grid, BLK, 0, stream>>>(w, psi);
    k_pass3<<<grid, BLK, 0, stream>>>(psi, out);
}

// Round 4
// 872.626 us; speedup vs baseline: 1.0296x; 1.0296x over previous
//
#include <hip/hip_runtime.h>
#include <utility>

// 16-wire statevector sim, batch 128. Register-blocked gate sweeps.
// Wire w <-> global bit (15-w). Per layer l (r=l+1):
//  pass1: pure-register: group global bits {15,14,15-r,14-r}:
//         H2(l-1) as register ctrl-swaps; Rot{0,1,r,r+1}; CNOT(0->r),(1->r+1)
//  pass2: chunk = fixed global bits {15,14}; LDS-staged register sweeps
//         S1{13..10} S2{9..6} S3{5..2} S4{3..0} (+S5{13..10} wraps, r>=3)
//  pass3: pure-register readout: H2(5) as ctrl-swaps; <Z_i>
// All global loads/stores coalesced (no per-lane address XOR — R3 lesson:
// scatter doubles HBM write traffic). LDS uses XOR swizzle u^=(u>>4)&15.

#define NW    16
#define BLK   1024
#define CHUNK 16384

// ---------- static_for ----------
template<class F, int... Is>
__device__ __forceinline__ void static_for_impl(F&& f, std::integer_sequence<int, Is...>) {
    (f(std::integral_constant<int, Is>{}), ...);
}
template<int N, class F>
__device__ __forceinline__ void static_for(F&& f) {
    static_for_impl(f, std::make_integer_sequence<int, N>{});
}

__device__ __forceinline__ int swz(int u) { return u ^ ((u >> 4) & 15); }

// ---------- gate primitives ----------
__device__ __forceinline__ void c2x2(float2& a0, float2& a1,
                                     float2 m00, float2 m01,
                                     float2 m10, float2 m11) {
    float2 r0, r1;
    r0.x = m00.x*a0.x - m00.y*a0.y + m01.x*a1.x - m01.y*a1.y;
    r0.y = m00.x*a0.y + m00.y*a0.x + m01.x*a1.y + m01.y*a1.x;
    r1.x = m10.x*a0.x - m10.y*a0.y + m11.x*a1.x - m11.y*a1.y;
    r1.y = m10.x*a0.y + m10.y*a0.x + m11.x*a1.y + m11.y*a1.x;
    a0 = r0; a1 = r1;
}

template<int Q>
__device__ __forceinline__ void rot_regs(float2 a[16], float2 m00, float2 m01,
                                         float2 m10, float2 m11) {
#pragma unroll
    for (int j = 0; j < 16; ++j)
        if (!((j >> Q) & 1))
            c2x2(a[j], a[j | (1 << Q)], m00, m01, m10, m11);
}

template<int QC, int QT>
__device__ __forceinline__ void cnot_inreg(float2 a[16]) {   // free: reg rename
#pragma unroll
    for (int j = 0; j < 16; ++j)
        if (((j >> QC) & 1) && !((j >> QT) & 1)) {
            float2 t = a[j]; a[j] = a[j | (1 << QT)]; a[j | (1 << QT)] = t;
        }
}

template<int QT>
__device__ __forceinline__ void cnot_ctrlout(float2 a[16], int ctrl) {
#pragma unroll
    for (int j = 0; j < 16; ++j)
        if (!((j >> QT) & 1)) {
            int j2 = j | (1 << QT);
            float2 x = a[j], y = a[j2];
            a[j].x  = ctrl ? y.x : x.x;  a[j].y  = ctrl ? y.y : x.y;
            a[j2].x = ctrl ? x.x : y.x;  a[j2].y = ctrl ? x.y : y.y;
        }
}

// Rot(phi,theta,omega) = RZ(omega) RY(theta) RZ(phi)
__device__ __forceinline__ void rot_mat(const float* ww, float2 m[4]) {
    float phi = ww[0], th = ww[1], om = ww[2];
    float ct, st;   sincosf(0.5f * th, &st, &ct);
    float cap, sap; sincosf(0.5f * (phi + om), &sap, &cap);
    float cam, sam; sincosf(0.5f * (phi - om), &sam, &cam);
    m[0] = make_float2( cap * ct, -sap * ct);
    m[1] = make_float2(-cam * st, -sam * st);
    m[2] = make_float2( cam * st, -sam * st);
    m[3] = make_float2( cap * ct,  sap * ct);
}

__device__ __forceinline__ void prep_gm(float2 (*gm)[4], const float* w, int l) {
    int t = threadIdx.x;
    if (t < NW) rot_mat(w + (l * NW + t) * 3, gm[t]);
}

// ---------- pass2 sweep gate driver ----------
// S<=4: returns wmask (LDS-write-address XOR fold, group-nibble space).
// S==5: applies wrap CNOTs as register ctrl-swaps, returns 0.
template<int L, int S>
__device__ __forceinline__ int sweep_gates(float2 a[16], const float2 (*gm)[4], int ub) {
    constexpr int r = L + 1;
    constexpr int base = (S == 2) ? 6 : (S == 3) ? 2 : (S == 4) ? 0 : 10;
    int wmask = 0;
    if constexpr (S <= 4) {
        constexpr int plo = (S == 1) ? 10 : (S == 2) ? 6 : (S == 3) ? 2 : 0;
        constexpr int phi = (S == 1) ? 13 : (S == 2) ? 9 : (S == 3) ? 5 : 1;
        // Rots, descending bit (wires of this partition; pass1 wires skipped)
        static_for<phi - plo + 1>([&](auto K) {
            constexpr int bb = phi - decltype(K)::value;
            if constexpr (bb != 15 - r && bb != 14 - r) {
                constexpr int wire = 15 - bb;
                rot_regs<bb - base>(a, gm[wire][0], gm[wire][1], gm[wire][2], gm[wire][3]);
            }
        });
        // ring CNOTs, ascending i: i=2..15-r, cb=15-i, tb=cb-r
        static_for<14 - r>([&](auto K) {
            constexpr int i  = 2 + decltype(K)::value;
            constexpr int cb = 15 - i, tb = cb - r;
            if constexpr (tb >= plo && tb <= phi) {
                if constexpr (cb <= base + 3) {
                    cnot_inreg<cb - base, tb - base>(a);        // control in group: free
                } else if constexpr (tb - r >= plo) {
                    cnot_ctrlout<tb - base>(a, (ub >> cb) & 1); // same-sweep successor
                } else {
                    wmask |= ((ub >> cb) & 1) << (tb - base);   // fold into LDS write addr
                }
            }
        });
    } else {
        // S5: wrap CNOTs i=18-r..15 (cb=15-i in ub, tb=31-i-r in group):
        // register ctrl-swaps so the global store stays coalesced (R3 lesson)
        static_for<(r >= 3) ? (r - 2) : 0>([&](auto K) {
            constexpr int i  = 18 - r + decltype(K)::value;
            constexpr int cb = 15 - i, tb = 31 - i - r;
            cnot_ctrlout<tb - 10>(a, (ub >> cb) & 1);
        });
    }
    return wmask;
}

// ---------- pass1: pure register, group global bits {15,14,g1,g0} ----------
template<int L>
__global__ __launch_bounds__(BLK, 4)
void k_pass1(const float* __restrict__ x, const float* __restrict__ w,
             float2* __restrict__ psi) {
    constexpr int r  = L + 1;
    constexpr int g1 = (L == 0) ? 13 : 15 - r;
    constexpr int g0 = (L == 0) ? 12 : 14 - r;
    const int b = blockIdx.x >> 2;
    const int T = ((blockIdx.x & 3) << 10) | threadIdx.x;   // 12-bit
    float2* g = psi + ((size_t)b << 16);

    // deposit T into the 12 non-group positions (0..13 minus {g1,g0})
    int sb;
    {
        constexpr int lobits  = g0;
        constexpr int midbits = g1 - 1 - g0;
        int lo  = T & ((1 << lobits) - 1);
        int mid = (T >> lobits) & ((1 << midbits) - 1);
        int hi  = T >> (lobits + midbits);
        sb = lo | (mid << (g0 + 1)) | (hi << (g1 + 1));
    }

    float2 m0[4], m1[4], mr[4], mr1[4];
    rot_mat(w + (L * NW + 0) * 3, m0);
    rot_mat(w + (L * NW + 1) * 3, m1);
    if constexpr (L == 0) {
        rot_mat(w + 2 * 3, mr);
    } else {
        rot_mat(w + (L * NW + r) * 3, mr);
        rot_mat(w + (L * NW + r + 1) * 3, mr1);
    }

    float2 a[16];
    if constexpr (L == 0) {
        // AngleEmbedding product state, built in registers
        float cv[NW], sv[NW];
#pragma unroll
        for (int wq = 0; wq < NW; ++wq)
            sincosf(0.5f * x[b * NW + wq], &sv[wq], &cv[wq]);
        float common = 1.0f;
#pragma unroll
        for (int wq = 4; wq < NW; ++wq) {
            int bit = (sb >> (15 - wq)) & 1;
            common *= bit ? sv[wq] : cv[wq];
        }
#pragma unroll
        for (int j = 0; j < 16; ++j) {
            float f0 = (j & 8) ? sv[0] : cv[0];
            float f1 = (j & 4) ? sv[1] : cv[1];
            float f2 = (j & 2) ? sv[2] : cv[2];
            float f3 = (j & 1) ? sv[3] : cv[3];
            a[j] = make_float2(common * f0 * f1 * f2 * f3, 0.0f);
        }
    } else {
        // coalesced loads (no address XOR), then H2(L-1) as register ctrl-swaps
#pragma unroll
        for (int j = 0; j < 16; ++j) {
            int s = sb | ((j & 1) << g0) | (((j >> 1) & 1) << g1)
                       | (((j >> 2) & 1) << 14) | (((j >> 3) & 1) << 15);
            a[j] = g[s];
        }
        // H2(L-1): rp=L. targets bits 15,14 = reg bits 3,2; ctrl bits L-1,L-2 in sb
        if constexpr (L >= 2) {
            cnot_ctrlout<3>(a, (sb >> (L - 1)) & 1);
            cnot_ctrlout<2>(a, (sb >> (L - 2)) & 1);
        } else {
            cnot_ctrlout<3>(a, sb & 1);    // L==1: only CNOT(15->0)
        }
    }

    rot_regs<3>(a, m0[0], m0[1], m0[2], m0[3]);   // Rot wire 0
    rot_regs<2>(a, m1[0], m1[1], m1[2], m1[3]);   // Rot wire 1
    if constexpr (L == 0) {
        rot_regs<1>(a, mr[0], mr[1], mr[2], mr[3]);  // Rot wire 2
        cnot_inreg<3, 2>(a);                          // CNOT(0->1)
        cnot_inreg<2, 1>(a);                          // CNOT(1->2)
    } else {
        rot_regs<1>(a, mr[0],  mr[1],  mr[2],  mr[3]);   // Rot wire r
        rot_regs<0>(a, mr1[0], mr1[1], mr1[2], mr1[3]);  // Rot wire r+1
        cnot_inreg<3, 1>(a);                              // CNOT(0->r)
        cnot_inreg<2, 0>(a);                              // CNOT(1->r+1)
    }

#pragma unroll
    for (int j = 0; j < 16; ++j) {
        int s = sb | ((j & 1) << g0) | (((j >> 1) & 1) << g1)
                   | (((j >> 2) & 1) << 14) | (((j >> 3) & 1) << 15);
        g[s] = a[j];
    }
}

// ---------- pass2: LDS-staged register sweeps, fixed global bits {15,14} ----------
template<int L>
__global__ __launch_bounds__(BLK, 4)
void k_pass2(const float* __restrict__ w, float2* __restrict__ psi) {
    constexpr int r = L + 1;
    __shared__ float2 lds[CHUNK];                 // XOR-swizzled, no padding
    __shared__ float2 gm[NW][4];
    const int b = blockIdx.x >> 2, c = blockIdx.x & 3;
    const int tid = threadIdx.x;
    float2* g = psi + ((size_t)b << 16) + ((size_t)c << 14);

    float2 a[16];

    // S1 loads first (hide latency under prep_gm + barrier)
    const int ub1 = tid;
#pragma unroll
    for (int j = 0; j < 16; ++j) a[j] = g[ub1 | (j << 10)];

    prep_gm(gm, w, L);
    __syncthreads();

    { // S1: group {13..10}: regs -> LDS
        int wm = sweep_gates<L, 1>(a, gm, ub1) << 10;
#pragma unroll
        for (int j = 0; j < 16; ++j)
            lds[swz((ub1 | (j << 10)) ^ wm)] = a[j];
    }
    __syncthreads();
    { // S2: group {9..6}
        const int ub = (tid & 63) | ((tid >> 6) << 10);
#pragma unroll
        for (int j = 0; j < 16; ++j) a[j] = lds[swz(ub | (j << 6))];
        int wm = sweep_gates<L, 2>(a, gm, ub) << 6;
#pragma unroll
        for (int j = 0; j < 16; ++j)
            lds[swz((ub | (j << 6)) ^ wm)] = a[j];
    }
    __syncthreads();
    { // S3: group {5..2}
        const int ub = (tid & 3) | ((tid >> 2) << 6);
#pragma unroll
        for (int j = 0; j < 16; ++j) a[j] = lds[swz(ub | (j << 2))];
        int wm = sweep_gates<L, 3>(a, gm, ub) << 2;
#pragma unroll
        for (int j = 0; j < 16; ++j)
            lds[swz((ub | (j << 2)) ^ wm)] = a[j];
    }
    __syncthreads();
    { // S4: group {3..0}
        const int ub = tid << 4;
#pragma unroll
        for (int j = 0; j < 16; ++j) a[j] = lds[swz(ub | j)];
        int wm = sweep_gates<L, 4>(a, gm, ub);
#pragma unroll
        for (int j = 0; j < 16; ++j)
            lds[swz((ub | j) ^ wm)] = a[j];
    }
    __syncthreads();
    if constexpr (r >= 3) {
        // S5: group {13..10}: wrap CNOTs as register ctrl-swaps, coalesced store
        const int ub = tid;
#pragma unroll
        for (int j = 0; j < 16; ++j) a[j] = lds[swz(ub | (j << 10))];
        (void)sweep_gates<L, 5>(a, gm, ub);
#pragma unroll
        for (int j = 0; j < 16; ++j) g[ub | (j << 10)] = a[j];
    } else {
        // plain copy LDS -> global (coalesced float4)
#pragma unroll
        for (int it = 0; it < 8; ++it) {
            int v = tid + it * BLK;
            int u = 2 * v;
            float2 lo = lds[swz(u)];
            float2 hi = lds[swz(u + 1)];
            reinterpret_cast<float4*>(g)[v] = make_float4(lo.x, lo.y, hi.x, hi.y);
        }
    }
}

// ---------- pass3: pure register readout, group {15,14,1,0} ----------
__global__ __launch_bounds__(BLK, 4)
void k_pass3(const float2* __restrict__ psi, float* __restrict__ out) {
    const int b = blockIdx.x >> 2;
    const int T = ((blockIdx.x & 3) << 10) | threadIdx.x;   // 12-bit
    const float2* g = psi + ((size_t)b << 16);
    const int sb = T << 2;                                   // non-group = bits 2..13

    float2 a[16];
#pragma unroll
    for (int jh = 0; jh < 4; ++jh) {
        const float4* p = reinterpret_cast<const float4*>(g + (sb | (jh << 14)));
        float4 v0 = p[0], v1 = p[1];
        a[jh * 4 + 0] = make_float2(v0.x, v0.y);
        a[jh * 4 + 1] = make_float2(v0.z, v0.w);
        a[jh * 4 + 2] = make_float2(v1.x, v1.y);
        a[jh * 4 + 3] = make_float2(v1.z, v1.w);
    }
    // H2(5): CNOT(w10->w0), CNOT(w11->w1): ctrl bits 5,4; targets reg bits 3,2
    cnot_ctrlout<3>(a, (sb >> 5) & 1);
    cnot_ctrlout<2>(a, (sb >> 4) & 1);

    float psum = 0.f, z0 = 0.f, z1 = 0.f, z14 = 0.f, z15 = 0.f;
#pragma unroll
    for (int j = 0; j < 16; ++j) {
        float2 v = a[j];
        float p = v.x * v.x + v.y * v.y;
        psum += p;
        z0  += (j & 8) ? -p : p;
        z1  += (j & 4) ? -p : p;
        z14 += (j & 2) ? -p : p;
        z15 += (j & 1) ? -p : p;
    }
    float z[NW];
    z[0] = z0; z[1] = z1; z[14] = z14; z[15] = z15;
#pragma unroll
    for (int i = 2; i < 14; ++i)
        z[i] = ((sb >> (15 - i)) & 1) ? -psum : psum;

    __shared__ float acc[NW];
    if (threadIdx.x < NW) acc[threadIdx.x] = 0.f;
    __syncthreads();
#pragma unroll
    for (int i = 0; i < NW; ++i) {
        float v = z[i];
#pragma unroll
        for (int off = 32; off > 0; off >>= 1) v += __shfl_down(v, off, 64);
        if ((threadIdx.x & 63) == 0) atomicAdd(&acc[i], v);
    }
    __syncthreads();
    if (threadIdx.x < NW) atomicAdd(&out[b * NW + threadIdx.x], acc[threadIdx.x]);
}

extern "C" void kernel_launch(void* const* d_in, const int* in_sizes, int n_in,
                              void* d_out, int out_size, void* d_ws, size_t ws_size,
                              hipStream_t stream) {
    const float* x = (const float*)d_in[0];   // (B, 16) float32
    const float* w = (const float*)d_in[1];   // (6, 16, 3) float32
    float* out = (float*)d_out;               // (B, 16) float32
    float2* psi = (float2*)d_ws;              // B * 65536 * 8 B = 64 MiB

    const int batch = in_sizes[0] / NW;
    const int grid  = batch * 4;

    hipMemsetAsync(d_out, 0, (size_t)out_size * sizeof(float), stream);

    k_pass1<0><<<grid, BLK, 0, stream>>>(x, w, psi);
    k_pass2<0><<<grid, BLK, 0, stream>>>(w, psi);
    k_pass1<1><<<grid, BLK, 0, stream>>>(x, w, psi);
    k_pass2<1><<<grid, BLK, 0, stream>>>(w, psi);
    k_pass1<2><<<grid, BLK, 0, stream>>>(x, w, psi);
    k_pass2<2><<<grid, BLK, 0, stream>>>(w, psi);
    k_pass1<3><<<grid, BLK, 0, stream>>>(x, w, psi);
    k_pass2<3><<<grid, BLK, 0, stream>>>(w, psi);
    k_pass1<4><<<grid, BLK, 0, stream>>>(x, w, psi);
    k_pass2<4><<<grid, BLK, 0, stream>>>(w, psi);
    k_pass1<5><<<grid, BLK, 0, stream>>>(x, w, psi);
    k_pass2<5><<<grid, BLK, 0, stream>>>(w, psi);
    k_pass3<<<grid, BLK, 0, stream>>>(psi, out);
}